// Round 6
// baseline (169.032 us; speedup 1.0000x reference)
//
#include <hip/hip_runtime.h>

// Problem constants (from reference): B=2, C=3, H=W=64, N=4096.
namespace {
constexpr int BB = 2;
constexpr int NN = 4096;
constexpr float LOG2E = 1.44269504088896340736f;
constexpr float T50 = 72.1347520444481703f;   // 50 * log2(e)
constexpr float T50SQ = T50 * T50;
constexpr int ICH = 32;   // i-chunks for p2t (32 colgroups x 32 = 1024 blocks)
constexpr int JCH = 32;   // j-chunks for p3t

// Workspace layout (floats), ~790 KB, L2-resident.
// w4   : float4[B*N] {T50*wx, T50*wy, T50*wz, 0}       tight stream for p1
// irec : 8 f / i : {u.x,u.y,u.z, T50^2|u|^2} {s*log2e (x3), mden}
// jrec : 12 f / j : {T50*w (x3), |tar|} {tar raw (x3), S_j} {src raw (x3), 0}
// mden = m' + log2(rowsum) (p1); S_j accumulated by p2 atomics (slot init 0 by setup)
constexpr int OFF_W4   = 0;
constexpr int OFF_IREC = 4 * BB * NN;
constexpr int OFF_JREC = 12 * BB * NN;
constexpr int OFF_NMAX = 24 * BB * NN;  // float[B] max_i |src_i| (uint-bits atomicMax)
}

__device__ __forceinline__ float fsqrt(float x) { return __builtin_amdgcn_sqrtf(x); }
__device__ __forceinline__ float fexp2(float x) {
#if __has_builtin(__builtin_amdgcn_exp2f)
  return __builtin_amdgcn_exp2f(x);
#else
  return exp2f(x);
#endif
}
__device__ __forceinline__ float flog2(float x) {
#if __has_builtin(__builtin_amdgcn_logf)
  return __builtin_amdgcn_logf(x);   // v_log_f32 = log2
#else
  return log2f(x);
#endif
}

// ---------------------------------------------------------------------------
// Setup: per-batch M = K R K^-1, o = K t; packed per-pixel records; max|src|.
// ---------------------------------------------------------------------------
__global__ __launch_bounds__(256) void k_setup(
    const float* __restrict__ fsrc, const float* __restrict__ ftar,
    const float* __restrict__ Kb, const float* __restrict__ Rb,
    const float* __restrict__ tb, float* __restrict__ ws) {
  int gid = blockIdx.x * 256 + threadIdx.x;
  if (gid >= BB * NN) return;
  int b = gid >> 12;
  int n = gid & (NN - 1);

  float K[9], R[9], t3[3];
#pragma unroll
  for (int k = 0; k < 9; k++) { K[k] = Kb[b * 9 + k]; R[k] = Rb[b * 9 + k]; }
#pragma unroll
  for (int k = 0; k < 3; k++) t3[k] = tb[b * 3 + k];

  // K^-1 via adjugate
  float c00 = K[4] * K[8] - K[5] * K[7];
  float c01 = K[5] * K[6] - K[3] * K[8];
  float c02 = K[3] * K[7] - K[4] * K[6];
  float det = K[0] * c00 + K[1] * c01 + K[2] * c02;
  float id = 1.0f / det;
  float Ki[9];
  Ki[0] = c00 * id; Ki[1] = (K[2] * K[7] - K[1] * K[8]) * id; Ki[2] = (K[1] * K[5] - K[2] * K[4]) * id;
  Ki[3] = c01 * id; Ki[4] = (K[0] * K[8] - K[2] * K[6]) * id; Ki[5] = (K[2] * K[3] - K[0] * K[5]) * id;
  Ki[6] = c02 * id; Ki[7] = (K[1] * K[6] - K[0] * K[7]) * id; Ki[8] = (K[0] * K[4] - K[1] * K[3]) * id;

  float RK[9];
#pragma unroll
  for (int i = 0; i < 3; i++)
#pragma unroll
    for (int j = 0; j < 3; j++)
      RK[i * 3 + j] = R[i * 3 + 0] * Ki[j] + R[i * 3 + 1] * Ki[3 + j] + R[i * 3 + 2] * Ki[6 + j];
  float M3[9];
#pragma unroll
  for (int i = 0; i < 3; i++)
#pragma unroll
    for (int j = 0; j < 3; j++)
      M3[i * 3 + j] = K[i * 3 + 0] * RK[j] + K[i * 3 + 1] * RK[3 + j] + K[i * 3 + 2] * RK[6 + j];
  float o0 = K[0] * t3[0] + K[1] * t3[1] + K[2] * t3[2];
  float o1 = K[3] * t3[0] + K[4] * t3[1] + K[5] * t3[2];
  float o2 = K[6] * t3[0] + K[7] * t3[1] + K[8] * t3[2];

  float sx = fsrc[b * 3 * NN + 0 * NN + n];
  float sy = fsrc[b * 3 * NN + 1 * NN + n];
  float sz = fsrc[b * 3 * NN + 2 * NN + n];
  float tx = ftar[b * 3 * NN + 0 * NN + n];
  float ty = ftar[b * 3 * NN + 1 * NN + n];
  float tz = ftar[b * 3 * NN + 2 * NN + n];

  float ux = sx - o0, uy = sy - o1, uz = sz - o2;
  float usq = ux * ux + uy * uy + uz * uz;

  float px = (float)(n >> 6), py = (float)(n & 63);
  float vx = M3[0] * px + M3[1] * py + M3[2];
  float vy = M3[3] * px + M3[4] * py + M3[5];
  float vz = M3[6] * px + M3[7] * py + M3[8];
  float invn = rsqrtf(vx * vx + vy * vy + vz * vz) * T50;  // fold T50 into w
  float wx = vx * invn, wy = vy * invn, wz = vz * invn;
  float tn = fsqrt(tx * tx + ty * ty + tz * tz);

  float4* w4 = (float4*)(ws + OFF_W4);
  float4* irec = (float4*)(ws + OFF_IREC);
  float4* jrec = (float4*)(ws + OFF_JREC);
  w4[gid] = make_float4(wx, wy, wz, 0.f);
  irec[gid * 2 + 0] = make_float4(ux, uy, uz, usq * T50SQ);
  irec[gid * 2 + 1] = make_float4(sx * LOG2E, sy * LOG2E, sz * LOG2E, 0.f);  // .w = mden (p1)
  jrec[gid * 3 + 0] = make_float4(wx, wy, wz, tn);
  jrec[gid * 3 + 1] = make_float4(tx, ty, tz, 0.f);  // .w = S_j accumulator (p2 atomics)
  jrec[gid * 3 + 2] = make_float4(sx, sy, sz, 0.f);

  // per-batch max |src| (blocks are single-batch: 4096 % 256 == 0)
  float ns = fsqrt(sx * sx + sy * sy + sz * sz);
#pragma unroll
  for (int off = 32; off; off >>= 1) ns = fmaxf(ns, __shfl_xor(ns, off));
  if ((threadIdx.x & 63) == 0)
    atomicMax((unsigned int*)(ws + OFF_NMAX + b), __float_as_uint(ns));
}

// ---------------------------------------------------------------------------
// Pass 1: row softmax stats over j (log2 domain). 1024 blocks, 8 rows, 4 waves
// split j 4 ways; 2x j-unroll. (Proven shape; transpose later if p2t/p3t win.)
// ---------------------------------------------------------------------------
__global__ __launch_bounds__(256, 4) void k_p1(float* __restrict__ ws) {
  __shared__ float sred[4][8];
  __shared__ float smax[8];
  const float4* irec = (const float4*)(ws + OFF_IREC);
  int tid = threadIdx.x, wid = tid >> 6, lane = tid & 63;
  int g0 = blockIdx.x * 8;
  int b = g0 >> 12;
  const float4* wb = (const float4*)(ws + OFF_W4) + b * NN;

  float ux[8], uy[8], uz[8], us[8];
#pragma unroll
  for (int r = 0; r < 8; r++) {
    float4 u = irec[(g0 + r) * 2];
    ux[r] = u.x; uy[r] = u.y; uz[r] = u.z; us[r] = u.w;
  }

  // Loop A: max d2' (no transcendentals), 2 j per iteration
  float mx[8] = {0.f, 0.f, 0.f, 0.f, 0.f, 0.f, 0.f, 0.f};
  for (int j = wid * 64 + lane; j < NN; j += 512) {
    float4 w0 = wb[j];
    float4 w1 = wb[j + 256];
#pragma unroll
    for (int r = 0; r < 8; r++) {
      float d0 = ux[r] * w0.x + uy[r] * w0.y + uz[r] * w0.z;
      float d1 = ux[r] * w1.x + uy[r] * w1.y + uz[r] * w1.z;
      mx[r] = fmaxf(mx[r], fmaxf(__builtin_fmaf(-d0, d0, us[r]),
                                 __builtin_fmaf(-d1, d1, us[r])));
    }
  }
#pragma unroll
  for (int off = 32; off; off >>= 1)
#pragma unroll
    for (int r = 0; r < 8; r++) mx[r] = fmaxf(mx[r], __shfl_xor(mx[r], off));
  if (lane == 0) {
#pragma unroll
    for (int r = 0; r < 8; r++) sred[wid][r] = mx[r];
  }
  __syncthreads();
  if (tid < 8)
    smax[tid] = fsqrt(fmaxf(fmaxf(fmaxf(sred[0][tid], sred[1][tid]),
                                  fmaxf(sred[2][tid], sred[3][tid])), 0.f));
  __syncthreads();
  float m[8];
#pragma unroll
  for (int r = 0; r < 8; r++) m[r] = smax[r];

  // Loop B: sum exp2(sqrt(d2') - m'), 2 j per iteration
  float s[8] = {0.f, 0.f, 0.f, 0.f, 0.f, 0.f, 0.f, 0.f};
  for (int j = wid * 64 + lane; j < NN; j += 512) {
    float4 w0 = wb[j];
    float4 w1 = wb[j + 256];
#pragma unroll
    for (int r = 0; r < 8; r++) {
      float d0 = ux[r] * w0.x + uy[r] * w0.y + uz[r] * w0.z;
      float d1 = ux[r] * w1.x + uy[r] * w1.y + uz[r] * w1.z;
      float q0 = fmaxf(__builtin_fmaf(-d0, d0, us[r]), 0.f);
      float q1 = fmaxf(__builtin_fmaf(-d1, d1, us[r]), 0.f);
      s[r] += fexp2(fsqrt(q0) - m[r]) + fexp2(fsqrt(q1) - m[r]);
    }
  }
#pragma unroll
  for (int off = 32; off; off >>= 1)
#pragma unroll
    for (int r = 0; r < 8; r++) s[r] += __shfl_xor(s[r], off);
  if (lane == 0) {
#pragma unroll
    for (int r = 0; r < 8; r++) sred[wid][r] = s[r];
  }
  __syncthreads();
  if (tid < 8) {
    float tot = sred[0][tid] + sred[1][tid] + sred[2][tid] + sred[3][tid];
    ws[OFF_IREC + (g0 + tid) * 8 + 7] = smax[tid] + flog2(tot);  // mden
  }
}

// ---------------------------------------------------------------------------
// Pass 2 (transposed): lane <-> column, serial loop over an i-chunk.
// Per-i record is wave-uniform -> scalar loads. No shuffles, no LDS.
// 32 colgroups x ICH chunks = 1024 blocks; atomicAdd partial S into jrec .w.
// ---------------------------------------------------------------------------
__global__ __launch_bounds__(256) void k_p2t(float* __restrict__ ws) {
  int tid = threadIdx.x;
  int g = blockIdx.x / ICH;        // colgroup: 256 consecutive cols
  int ic = blockIdx.x % ICH;       // i-chunk
  int col = g * 256 + tid;
  int b = col >> 12;
  int base = b * NN;
  const float4* irec = (const float4*)(ws + OFF_IREC);
  const float4* jrec = (const float4*)(ws + OFF_JREC);
  float maxns2 = ws[OFF_NMAX + b] * LOG2E;

  float4 q0 = jrec[col * 3 + 0];   // T50*w, |tar|   (per-lane)
  float4 q1 = jrec[col * 3 + 1];   // tar raw
  float wx = q0.x, wy = q0.y, wz = q0.z;
  float Mb2 = maxns2 * q0.w;       // deterministic per-col shift (same all chunks)
  float tx = q1.x, ty = q1.y, tz = q1.z;

  float S = 0.f;
  int i0 = base + ic * (NN / ICH);
#pragma unroll 4
  for (int it = 0; it < NN / ICH; ++it) {
    int idx = i0 + it;                   // wave-uniform -> s_load_dwordx4
    float4 u = irec[idx * 2 + 0];        // u, T50^2|u|^2
    float4 sq = irec[idx * 2 + 1];       // s*log2e, mden
    float dot = u.x * wx + u.y * wy + u.z * wz;
    float d2 = fmaxf(__builtin_fmaf(-dot, dot, u.w), 0.f);
    float en = fexp2(fsqrt(d2) - sq.w);
    float wgt = 1.f - en;
    float A2 = sq.x * tx + sq.y * ty + sq.z * tz;
    S += fexp2(__builtin_fmaf(A2, wgt, -Mb2));
  }
  atomicAdd(ws + OFF_JREC + col * 12 + 7, S);
}

// ---------------------------------------------------------------------------
// Pass 3 (transposed): lane <-> row, serial loop over a j-chunk.
// Per-j record wave-uniform -> scalar loads; acc lane-private; atomicAdd out.
// 32 rowgroups x JCH chunks = 1024 blocks.
// ---------------------------------------------------------------------------
__global__ __launch_bounds__(256) void k_p3t(const float* __restrict__ ws,
                                             float* __restrict__ out) {
  int tid = threadIdx.x;
  int g = blockIdx.x / JCH;        // rowgroup: 256 consecutive rows
  int jc = blockIdx.x % JCH;       // j-chunk
  int row = g * 256 + tid;
  int b = row >> 12;
  int base = b * NN;
  const float4* irec = (const float4*)(ws + OFF_IREC);
  const float4* jrec = (const float4*)(ws + OFF_JREC);
  float maxns2 = ws[OFF_NMAX + b] * LOG2E;

  float4 u = irec[row * 2 + 0];    // per-lane row state
  float4 sq = irec[row * 2 + 1];   // s*log2e, mden
  float a0 = 0.f, a1 = 0.f, a2 = 0.f;

  int j0 = base + jc * (NN / JCH);
#pragma unroll 2
  for (int it = 0; it < NN / JCH; ++it) {
    int idx = j0 + it;                   // wave-uniform -> s_load_dwordx4
    float4 q0 = jrec[idx * 3 + 0];       // T50*w, |tar|
    float4 q1 = jrec[idx * 3 + 1];       // tar raw, S_j
    float4 q2 = jrec[idx * 3 + 2];       // src raw
    float cst = __builtin_fmaf(maxns2, q0.w, flog2(q1.w));  // Mb2_j + log2(S_j)
    float dot = u.x * q0.x + u.y * q0.y + u.z * q0.z;
    float d2 = fmaxf(__builtin_fmaf(-dot, dot, u.w), 0.f);
    float en = fexp2(fsqrt(d2) - sq.w);
    float wgt = 1.f - en;
    float A2 = sq.x * q1.x + sq.y * q1.y + sq.z * q1.z;
    float p = fexp2(__builtin_fmaf(A2, wgt, -cst));
    a0 = __builtin_fmaf(p, q2.x, a0);
    a1 = __builtin_fmaf(p, q2.y, a1);
    a2 = __builtin_fmaf(p, q2.z, a2);
  }
  // out layout: out[b*N*3 + i*3 + c] = out[row*3 + c]
  atomicAdd(out + row * 3 + 0, a0);
  atomicAdd(out + row * 3 + 1, a1);
  atomicAdd(out + row * 3 + 2, a2);
}

extern "C" void kernel_launch(void* const* d_in, const int* in_sizes, int n_in,
                              void* d_out, int out_size, void* d_ws, size_t ws_size,
                              hipStream_t stream) {
  (void)in_sizes; (void)n_in; (void)ws_size;
  const float* ftar = (const float*)d_in[0];
  const float* fsrc = (const float*)d_in[1];
  const float* K = (const float*)d_in[2];
  const float* R = (const float*)d_in[3];
  const float* t = (const float*)d_in[4];
  float* ws = (float*)d_ws;
  float* out = (float*)d_out;

  // zero the per-batch norm-max slots + output (p3t merges chunks via atomicAdd)
  hipMemsetAsync((char*)d_ws + OFF_NMAX * sizeof(float), 0, BB * sizeof(float), stream);
  hipMemsetAsync(d_out, 0, out_size, stream);

  k_setup<<<dim3(32), dim3(256), 0, stream>>>(fsrc, ftar, K, R, t, ws);
  k_p1<<<dim3(1024), dim3(256), 0, stream>>>(ws);
  k_p2t<<<dim3(32 * ICH), dim3(256), 0, stream>>>(ws);
  k_p3t<<<dim3(32 * JCH), dim3(256), 0, stream>>>(ws, out);
}

// Round 9
// 127.448 us; speedup vs baseline: 1.3263x; 1.3263x over previous
//
#include <hip/hip_runtime.h>

// Problem constants (from reference): B=2, C=3, H=W=64, N=4096.
namespace {
constexpr int BB = 2;
constexpr int NN = 4096;
constexpr float LOG2E = 1.44269504088896340736f;
constexpr float T50 = 72.1347520444481703f;   // 50 * log2(e)
constexpr float T50SQ = T50 * T50;

// Workspace layout (floats), ~790 KB, L2-resident.
// w4   : float4[B*N] {T50*wx, T50*wy, T50*wz, 0}       tight stream for p1
// irec : 8 f / i : {u.x,u.y,u.z, T50^2|u|^2} {s*log2e (x3), mden}
// jrec : 12 f / j : {T50*w (x3), |tar|} {tar raw (x3), S_j} {src raw (x3), 0}
// mden = m' + log2(rowsum) (p1); S_j accumulated by p2 atomics (slot init 0 by setup)
constexpr int OFF_W4   = 0;
constexpr int OFF_IREC = 4 * BB * NN;
constexpr int OFF_JREC = 12 * BB * NN;
constexpr int OFF_NMAX = 24 * BB * NN;  // float[B] max_i |src_i| (uint-bits atomicMax)
}

__device__ __forceinline__ float fsqrt(float x) { return __builtin_amdgcn_sqrtf(x); }
__device__ __forceinline__ float fexp2(float x) {
#if __has_builtin(__builtin_amdgcn_exp2f)
  return __builtin_amdgcn_exp2f(x);
#else
  return exp2f(x);
#endif
}
__device__ __forceinline__ float flog2(float x) {
#if __has_builtin(__builtin_amdgcn_logf)
  return __builtin_amdgcn_logf(x);   // v_log_f32 = log2
#else
  return log2f(x);
#endif
}

// ---------------------------------------------------------------------------
// Setup: per-batch M = K R K^-1, o = K t; packed per-pixel records; max|src|.
// ---------------------------------------------------------------------------
__global__ __launch_bounds__(256) void k_setup(
    const float* __restrict__ fsrc, const float* __restrict__ ftar,
    const float* __restrict__ Kb, const float* __restrict__ Rb,
    const float* __restrict__ tb, float* __restrict__ ws) {
  int gid = blockIdx.x * 256 + threadIdx.x;
  if (gid >= BB * NN) return;
  int b = gid >> 12;
  int n = gid & (NN - 1);

  float K[9], R[9], t3[3];
#pragma unroll
  for (int k = 0; k < 9; k++) { K[k] = Kb[b * 9 + k]; R[k] = Rb[b * 9 + k]; }
#pragma unroll
  for (int k = 0; k < 3; k++) t3[k] = tb[b * 3 + k];

  // K^-1 via adjugate
  float c00 = K[4] * K[8] - K[5] * K[7];
  float c01 = K[5] * K[6] - K[3] * K[8];
  float c02 = K[3] * K[7] - K[4] * K[6];
  float det = K[0] * c00 + K[1] * c01 + K[2] * c02;
  float id = 1.0f / det;
  float Ki[9];
  Ki[0] = c00 * id; Ki[1] = (K[2] * K[7] - K[1] * K[8]) * id; Ki[2] = (K[1] * K[5] - K[2] * K[4]) * id;
  Ki[3] = c01 * id; Ki[4] = (K[0] * K[8] - K[2] * K[6]) * id; Ki[5] = (K[2] * K[3] - K[0] * K[5]) * id;
  Ki[6] = c02 * id; Ki[7] = (K[1] * K[6] - K[0] * K[7]) * id; Ki[8] = (K[0] * K[4] - K[1] * K[3]) * id;

  float RK[9];
#pragma unroll
  for (int i = 0; i < 3; i++)
#pragma unroll
    for (int j = 0; j < 3; j++)
      RK[i * 3 + j] = R[i * 3 + 0] * Ki[j] + R[i * 3 + 1] * Ki[3 + j] + R[i * 3 + 2] * Ki[6 + j];
  float M3[9];
#pragma unroll
  for (int i = 0; i < 3; i++)
#pragma unroll
    for (int j = 0; j < 3; j++)
      M3[i * 3 + j] = K[i * 3 + 0] * RK[j] + K[i * 3 + 1] * RK[3 + j] + K[i * 3 + 2] * RK[6 + j];
  float o0 = K[0] * t3[0] + K[1] * t3[1] + K[2] * t3[2];
  float o1 = K[3] * t3[0] + K[4] * t3[1] + K[5] * t3[2];
  float o2 = K[6] * t3[0] + K[7] * t3[1] + K[8] * t3[2];

  float sx = fsrc[b * 3 * NN + 0 * NN + n];
  float sy = fsrc[b * 3 * NN + 1 * NN + n];
  float sz = fsrc[b * 3 * NN + 2 * NN + n];
  float tx = ftar[b * 3 * NN + 0 * NN + n];
  float ty = ftar[b * 3 * NN + 1 * NN + n];
  float tz = ftar[b * 3 * NN + 2 * NN + n];

  float ux = sx - o0, uy = sy - o1, uz = sz - o2;
  float usq = ux * ux + uy * uy + uz * uz;

  float px = (float)(n >> 6), py = (float)(n & 63);
  float vx = M3[0] * px + M3[1] * py + M3[2];
  float vy = M3[3] * px + M3[4] * py + M3[5];
  float vz = M3[6] * px + M3[7] * py + M3[8];
  float invn = rsqrtf(vx * vx + vy * vy + vz * vz) * T50;  // fold T50 into w
  float wx = vx * invn, wy = vy * invn, wz = vz * invn;
  float tn = fsqrt(tx * tx + ty * ty + tz * tz);

  float4* w4 = (float4*)(ws + OFF_W4);
  float4* irec = (float4*)(ws + OFF_IREC);
  float4* jrec = (float4*)(ws + OFF_JREC);
  w4[gid] = make_float4(wx, wy, wz, 0.f);
  irec[gid * 2 + 0] = make_float4(ux, uy, uz, usq * T50SQ);
  irec[gid * 2 + 1] = make_float4(sx * LOG2E, sy * LOG2E, sz * LOG2E, 0.f);  // .w = mden (p1)
  jrec[gid * 3 + 0] = make_float4(wx, wy, wz, tn);
  jrec[gid * 3 + 1] = make_float4(tx, ty, tz, 0.f);  // .w = S_j accumulator (p2 atomics)
  jrec[gid * 3 + 2] = make_float4(sx, sy, sz, 0.f);

  // per-batch max |src| (blocks are single-batch: 4096 % 256 == 0)
  float ns = fsqrt(sx * sx + sy * sy + sz * sz);
#pragma unroll
  for (int off = 32; off; off >>= 1) ns = fmaxf(ns, __shfl_xor(ns, off));
  if ((threadIdx.x & 63) == 0)
    atomicMax((unsigned int*)(ws + OFF_NMAX + b), __float_as_uint(ns));
}

// ---------------------------------------------------------------------------
// Pass 1: row softmax stats over j (log2 domain). 1024 blocks, 8 rows, 4 waves
// split j 4 ways; explicit 1-deep load rotation (prefetch next j's w).
// ---------------------------------------------------------------------------
__global__ __launch_bounds__(256, 4) void k_p1(float* __restrict__ ws) {
  __shared__ float sred[4][8];
  __shared__ float smax[8];
  const float4* irec = (const float4*)(ws + OFF_IREC);
  int tid = threadIdx.x, wid = tid >> 6, lane = tid & 63;
  int g0 = blockIdx.x * 8;
  int b = g0 >> 12;
  const float4* wb = (const float4*)(ws + OFF_W4) + b * NN;
  int j0 = wid * 64 + lane;

  float ux[8], uy[8], uz[8], us[8];
#pragma unroll
  for (int r = 0; r < 8; r++) {
    float4 u = irec[(g0 + r) * 2];
    ux[r] = u.x; uy[r] = u.y; uz[r] = u.z; us[r] = u.w;
  }

  // Loop A: max d2' (no transcendentals), rotated prefetch. 16 iters.
  float mx[8] = {0.f, 0.f, 0.f, 0.f, 0.f, 0.f, 0.f, 0.f};
  {
    float4 wc = wb[j0];
#pragma unroll
    for (int it = 0; it < 16; ++it) {
      float4 wn;
      if (it < 15) wn = wb[j0 + (it + 1) * 256];   // in flight across compute
#pragma unroll
      for (int r = 0; r < 8; r++) {
        float dot = ux[r] * wc.x + uy[r] * wc.y + uz[r] * wc.z;
        mx[r] = fmaxf(mx[r], __builtin_fmaf(-dot, dot, us[r]));
      }
      wc = wn;
    }
  }
#pragma unroll
  for (int off = 32; off; off >>= 1)
#pragma unroll
    for (int r = 0; r < 8; r++) mx[r] = fmaxf(mx[r], __shfl_xor(mx[r], off));
  if (lane == 0) {
#pragma unroll
    for (int r = 0; r < 8; r++) sred[wid][r] = mx[r];
  }
  __syncthreads();
  if (tid < 8)
    smax[tid] = fsqrt(fmaxf(fmaxf(fmaxf(sred[0][tid], sred[1][tid]),
                                  fmaxf(sred[2][tid], sred[3][tid])), 0.f));
  __syncthreads();
  float m[8];
#pragma unroll
  for (int r = 0; r < 8; r++) m[r] = smax[r];

  // Loop B: sum exp2(sqrt(d2') - m'), rotated prefetch. 16 iters.
  float s[8] = {0.f, 0.f, 0.f, 0.f, 0.f, 0.f, 0.f, 0.f};
  {
    float4 wc = wb[j0];
#pragma unroll
    for (int it = 0; it < 16; ++it) {
      float4 wn;
      if (it < 15) wn = wb[j0 + (it + 1) * 256];
#pragma unroll
      for (int r = 0; r < 8; r++) {
        float dot = ux[r] * wc.x + uy[r] * wc.y + uz[r] * wc.z;
        float d2 = fmaxf(__builtin_fmaf(-dot, dot, us[r]), 0.f);
        s[r] += fexp2(fsqrt(d2) - m[r]);
      }
      wc = wn;
    }
  }
#pragma unroll
  for (int off = 32; off; off >>= 1)
#pragma unroll
    for (int r = 0; r < 8; r++) s[r] += __shfl_xor(s[r], off);
  if (lane == 0) {
#pragma unroll
    for (int r = 0; r < 8; r++) sred[wid][r] = s[r];
  }
  __syncthreads();
  if (tid < 8) {
    float tot = sred[0][tid] + sred[1][tid] + sred[2][tid] + sred[3][tid];
    ws[OFF_IREC + (g0 + tid) * 8 + 7] = smax[tid] + flog2(tot);  // mden
  }
}

// ---------------------------------------------------------------------------
// Pass 2: partial column sums over half the i-range. 2048 blocks:
// colgroup = bid>>1 (8 cols), half = bid&1. Rotated prefetch (8 iters).
// atomicAdd partial S into jrec .w.
// ---------------------------------------------------------------------------
__global__ __launch_bounds__(256, 4) void k_p2(float* __restrict__ ws) {
  __shared__ float sred[4][8];
  const float4* irec = (const float4*)(ws + OFF_IREC);
  const float4* jrec = (const float4*)(ws + OFF_JREC);
  int tid = threadIdx.x, wid = tid >> 6, lane = tid & 63;
  int c0 = (blockIdx.x >> 1) * 8;
  int half = blockIdx.x & 1;
  int b = c0 >> 12;
  int base = b * NN;
  float maxns2 = ws[OFF_NMAX + b] * LOG2E;

  float wx[8], wy[8], wz[8], tx[8], ty[8], tz[8], Mb2[8];
#pragma unroll
  for (int r = 0; r < 8; r++) {
    float4 q0 = jrec[(c0 + r) * 3 + 0];
    float4 q1 = jrec[(c0 + r) * 3 + 1];
    wx[r] = q0.x; wy[r] = q0.y; wz[r] = q0.z;
    Mb2[r] = maxns2 * q0.w;    // deterministic per-col shift (same in both halves)
    tx[r] = q1.x; ty[r] = q1.y; tz[r] = q1.z;
  }

  float S[8] = {0.f, 0.f, 0.f, 0.f, 0.f, 0.f, 0.f, 0.f};
  int i0 = base + half * (NN / 2) + wid * 64 + lane;
  {
    float4 uc = irec[i0 * 2 + 0];
    float4 qc = irec[i0 * 2 + 1];
#pragma unroll
    for (int it = 0; it < 8; ++it) {
      float4 un, qn;
      if (it < 7) {
        int idx = i0 + (it + 1) * 256;
        un = irec[idx * 2 + 0];
        qn = irec[idx * 2 + 1];
      }
#pragma unroll
      for (int r = 0; r < 8; r++) {
        float dot = uc.x * wx[r] + uc.y * wy[r] + uc.z * wz[r];
        float d2 = fmaxf(__builtin_fmaf(-dot, dot, uc.w), 0.f);
        float en = fexp2(fsqrt(d2) - qc.w);
        float wgt = 1.f - en;
        float A2 = qc.x * tx[r] + qc.y * ty[r] + qc.z * tz[r];
        S[r] += fexp2(__builtin_fmaf(A2, wgt, -Mb2[r]));
      }
      uc = un; qc = qn;
    }
  }
#pragma unroll
  for (int off = 32; off; off >>= 1)
#pragma unroll
    for (int r = 0; r < 8; r++) S[r] += __shfl_xor(S[r], off);
  if (lane == 0) {
#pragma unroll
    for (int r = 0; r < 8; r++) sred[wid][r] = S[r];
  }
  __syncthreads();
  if (tid < 8) {
    float tot = sred[0][tid] + sred[1][tid] + sred[2][tid] + sred[3][tid];
    atomicAdd(ws + OFF_JREC + (c0 + tid) * 12 + 7, tot);  // S_j += partial
  }
}

// ---------------------------------------------------------------------------
// Pass 3: out[b,i,c] += sum_{j in half} exp2(A2*wgt - Mb2_j - log2(S_j))*src[c,j].
// 2048 blocks: rowgroup = bid>>1 (8 rows), half = bid&1. Rotated prefetch.
// atomicAdd into memset-zeroed out.
// ---------------------------------------------------------------------------
__global__ __launch_bounds__(256, 4) void k_p3(const float* __restrict__ ws,
                                               float* __restrict__ out) {
  __shared__ float sacc[4][24];
  const float4* irec = (const float4*)(ws + OFF_IREC);
  const float4* jrec = (const float4*)(ws + OFF_JREC);
  int tid = threadIdx.x, wid = tid >> 6, lane = tid & 63;
  int g0 = (blockIdx.x >> 1) * 8;
  int half = blockIdx.x & 1;
  int b = g0 >> 12;
  int base = b * NN;
  float maxns2 = ws[OFF_NMAX + b] * LOG2E;

  float ux[8], uy[8], uz[8], us[8], ml[8], s2x[8], s2y[8], s2z[8];
#pragma unroll
  for (int r = 0; r < 8; r++) {
    float4 u = irec[(g0 + r) * 2 + 0];
    float4 sq = irec[(g0 + r) * 2 + 1];
    ux[r] = u.x; uy[r] = u.y; uz[r] = u.z; us[r] = u.w;
    s2x[r] = sq.x; s2y[r] = sq.y; s2z[r] = sq.z; ml[r] = sq.w;
  }
  float acc[8][3];
#pragma unroll
  for (int r = 0; r < 8; r++) { acc[r][0] = 0.f; acc[r][1] = 0.f; acc[r][2] = 0.f; }

  int j0 = base + half * (NN / 2) + wid * 64 + lane;
  {
    float4 q0c = jrec[j0 * 3 + 0];
    float4 q1c = jrec[j0 * 3 + 1];
    float4 q2c = jrec[j0 * 3 + 2];
#pragma unroll
    for (int it = 0; it < 8; ++it) {
      float4 q0n, q1n, q2n;
      if (it < 7) {
        int idx = j0 + (it + 1) * 256;
        q0n = jrec[idx * 3 + 0];
        q1n = jrec[idx * 3 + 1];
        q2n = jrec[idx * 3 + 2];
      }
      float cst = __builtin_fmaf(maxns2, q0c.w, flog2(q1c.w));  // Mb2_j + log2(S_j)
#pragma unroll
      for (int r = 0; r < 8; r++) {
        float dot = ux[r] * q0c.x + uy[r] * q0c.y + uz[r] * q0c.z;
        float d2 = fmaxf(__builtin_fmaf(-dot, dot, us[r]), 0.f);
        float en = fexp2(fsqrt(d2) - ml[r]);
        float wgt = 1.f - en;
        float A2 = s2x[r] * q1c.x + s2y[r] * q1c.y + s2z[r] * q1c.z;
        float p = fexp2(__builtin_fmaf(A2, wgt, -cst));
        acc[r][0] = __builtin_fmaf(p, q2c.x, acc[r][0]);
        acc[r][1] = __builtin_fmaf(p, q2c.y, acc[r][1]);
        acc[r][2] = __builtin_fmaf(p, q2c.z, acc[r][2]);
      }
      q0c = q0n; q1c = q1n; q2c = q2n;
    }
  }
#pragma unroll
  for (int off = 32; off; off >>= 1)
#pragma unroll
    for (int r = 0; r < 8; r++) {
      acc[r][0] += __shfl_xor(acc[r][0], off);
      acc[r][1] += __shfl_xor(acc[r][1], off);
      acc[r][2] += __shfl_xor(acc[r][2], off);
    }
  if (lane == 0) {
#pragma unroll
    for (int r = 0; r < 8; r++) {
      sacc[wid][r * 3 + 0] = acc[r][0];
      sacc[wid][r * 3 + 1] = acc[r][1];
      sacc[wid][r * 3 + 2] = acc[r][2];
    }
  }
  __syncthreads();
  if (tid < 24) {
    float v = sacc[0][tid] + sacc[1][tid] + sacc[2][tid] + sacc[3][tid];
    atomicAdd(out + g0 * 3 + tid, v);
  }
}

extern "C" void kernel_launch(void* const* d_in, const int* in_sizes, int n_in,
                              void* d_out, int out_size, void* d_ws, size_t ws_size,
                              hipStream_t stream) {
  (void)in_sizes; (void)n_in; (void)ws_size;
  const float* ftar = (const float*)d_in[0];
  const float* fsrc = (const float*)d_in[1];
  const float* K = (const float*)d_in[2];
  const float* R = (const float*)d_in[3];
  const float* t = (const float*)d_in[4];
  float* ws = (float*)d_ws;
  float* out = (float*)d_out;

  // zero the per-batch norm-max slots + output (p3 merges halves via atomicAdd)
  hipMemsetAsync((char*)d_ws + OFF_NMAX * sizeof(float), 0, BB * sizeof(float), stream);
  hipMemsetAsync(d_out, 0, out_size, stream);

  k_setup<<<dim3(32), dim3(256), 0, stream>>>(fsrc, ftar, K, R, t, ws);
  k_p1<<<dim3(1024), dim3(256), 0, stream>>>(ws);
  k_p2<<<dim3(2048), dim3(256), 0, stream>>>(ws);
  k_p3<<<dim3(2048), dim3(256), 0, stream>>>(ws, out);
}